// Round 6
// baseline (224.819 us; speedup 1.0000x reference)
//
#include <hip/hip_runtime.h>

// Fused separable 11x11 gaussian + SSIM/charb/MSE, wave-streaming form.
// R11: R10 schedule (STRH=64, 3 blocks/CU, depth-2 prefetch, single LDS
// row buffer, launch_bounds(256,2)) + two VALU-count cuts:
// 1) COMMIT precomputes (x, y, x^2+y^2, x*y) per element ONCE and stores
//    float4 in LDS (ds_write_b128). R10's TAPS recomputed the products
//    per tap per lane: 33 of 77 tap-VALU were redundant (products depend
//    only on the element, not the tap). TAPS is now 11 ds_read_b128 +
//    pure accumulation.
// 2) Packed f32: (hx,hy) accumulates the (x,y) pair and (hs,hp) the
//    (s,p) pair with the same broadcast weight -> v_pk_fma_f32 via
//    clang ext_vector_type(2) + __builtin_elementwise_fma. TAPS 44->22
//    accum instrs, FINALIZE 44->22.
// Static interior step ~156 -> ~82 VALU instrs; predicted 72 -> 52-62us.
// R10 post-mortem: 778 cy/step-slot = 537 VALU + 241 residual stall; the
// VALU count is now the floor, so cut it.
// Schedule (unchanged from R10, verified): 11 prologue + 11 + 2x22 + 8
// epilogue steps; ring index u=i%11 and prefetch-set parity i&1 literal
// everywhere; depth-2 register prefetch (COMMIT set i&1 loaded at step
// i-2, issue row r+2 into same set); boundary masking at commit-site.
// Ring algebra: step i (u=i%11) -> h slot u; finalize at i>=10 emits row
// o=r-5 with weight GW[(u-s) mod 11] (GW symmetric); center diff
// dring[u] read 5 steps later at (u+6)%11. Out-of-range rows give h=0.

#define IMG    512
#define RAD    5
#define KW     11
#define STRH   64
#define ROWE   74                 // halo row entries (64 + 2*5)
#define PLANE  (IMG * IMG)

#define C1F  1e-4f
#define C2F  9e-4f
#define EPS2 1e-12f

#define W0 0.00102838f
#define W1 0.00759876f
#define W2 0.03600076f
#define W3 0.10936067f
#define W4 0.21300537f
#define W5 0.26601297f

typedef float f32x2 __attribute__((ext_vector_type(2)));

__global__ __launch_bounds__(256, 2)
void CombinedLossSSIMCharbMSE_81372450390186_kernel(
    const float* __restrict__ pred,
    const float* __restrict__ target,
    float* __restrict__ out)
{
    const float GW[KW] = {W0, W1, W2, W3, W4, W5, W4, W3, W2, W1, W0};

    __shared__ float4 rbf[4 * ROWE];  // 4 waves x 1 float4 row, 4736 B

    const int lane = threadIdx.x & 63;
    const int wav  = threadIdx.x >> 6;
    const int wid  = (blockIdx.x << 2) | wav;   // global wave id
    const int plane = wid >> 6;                 // 64 waves per plane
    const int tile  = (wid >> 3) & 7;           // 8 row-tiles of 64
    const int strip = wid & 7;                  // 8 col-strips of 64
    const int col0 = strip << 6;
    const int row0 = tile << 6;
    const int pbase = plane * PLANE;

    // Column geometry (constant across rows). Entry e <-> col col0-5+e.
    const int  cA  = col0 - RAD + lane;         // entries 0..63
    const bool okA = (cA >= 0) & (cA < IMG);
    const int  cAc = min(max(cA, 0), IMG - 1);
    const int  cB  = col0 + 59 + lane;          // entries 64..73 (lanes 0..9)
    const bool okB = cB < IMG;
    const int  cBc = min(cB, IMG - 1);
    const bool doB = lane < 10;

    const int wb = wav * ROWE;                  // LDS row base (single buf)

    f32x2 hxy[KW], hsp[KW];                     // paired h-rings
    float dring[KW];
#pragma unroll
    for (int s = 0; s < KW; ++s) {
        hxy[s] = (f32x2){0.f, 0.f};
        hsp[s] = (f32x2){0.f, 0.f};
        dring[s] = 0.f;
    }

    // Two prefetch register sets (depth 2), ping-ponged by step parity.
    float pA0 = 0.f, tA0 = 0.f, pB0 = 0.f, tB0 = 0.f;
    float pA1 = 0.f, tA1 = 0.f, pB1 = 0.f, tB1 = 0.f;

#define LOADR(ss, rr) do {                                                  \
        const int _b = pbase + (rr) * IMG;                                  \
        pA##ss = pred[_b + cAc];                                            \
        tA##ss = target[_b + cAc];                                          \
        if (doB) {                                                          \
            pB##ss = pred[_b + cBc];                                        \
            tB##ss = target[_b + cBc];                                      \
        }                                                                   \
    } while (0)

    // Mask at commit, derive (s,p) from masked values (auto-zeroed).
#define COMMITR(ss) do {                                                    \
        const float _mx = okA ? pA##ss : 0.f;                               \
        const float _my = okA ? tA##ss : 0.f;                               \
        float4 _v;                                                          \
        _v.x = _mx; _v.y = _my;                                             \
        _v.z = fmaf(_mx, _mx, _my * _my); _v.w = _mx * _my;                 \
        rbf[wb + lane] = _v;                                                \
        if (doB) {                                                          \
            const float _bx = okB ? pB##ss : 0.f;                           \
            const float _by = okB ? tB##ss : 0.f;                           \
            float4 _u;                                                      \
            _u.x = _bx; _u.y = _by;                                         \
            _u.z = fmaf(_bx, _bx, _by * _by); _u.w = _bx * _by;             \
            rbf[wb + 64 + lane] = _u;                                       \
        }                                                                   \
        __builtin_amdgcn_wave_barrier();  /* keep write->read order */      \
    } while (0)

#define TAPS(uu) do {                                                       \
        f32x2 _axy = (f32x2){0.f, 0.f};                                     \
        f32x2 _asp = (f32x2){0.f, 0.f};                                     \
        float _d5 = 0.f;                                                    \
        _Pragma("unroll")                                                   \
        for (int _d = 0; _d < KW; ++_d) {                                   \
            const float4 _t = rbf[wb + lane + _d];                          \
            if (_d == RAD) _d5 = _t.x - _t.y;                               \
            const f32x2 _w = {GW[_d], GW[_d]};                              \
            const f32x2 _xy = {_t.x, _t.y};                                 \
            const f32x2 _sp = {_t.z, _t.w};                                 \
            _axy = __builtin_elementwise_fma(_w, _xy, _axy);                \
            _asp = __builtin_elementwise_fma(_w, _sp, _asp);                \
        }                                                                   \
        hxy[uu] = _axy; hsp[uu] = _asp;                                     \
        dring[uu] = _d5;               /* center diff, used at step i+5 */  \
    } while (0)

#define ZERO_H(uu) do {                                                     \
        hxy[uu] = (f32x2){0.f, 0.f}; hsp[uu] = (f32x2){0.f, 0.f};           \
    } while (0)

#define FINALIZE(uu, oo) do {                                               \
        f32x2 _vxy = (f32x2){0.f, 0.f};                                     \
        f32x2 _vsp = (f32x2){0.f, 0.f};                                     \
        _Pragma("unroll")                                                   \
        for (int _s = 0; _s < KW; ++_s) {                                   \
            const float _wv = GW[((uu) - _s + KW) % KW];                    \
            const f32x2 _wp = {_wv, _wv};                                   \
            _vxy = __builtin_elementwise_fma(_wp, hxy[_s], _vxy);           \
            _vsp = __builtin_elementwise_fma(_wp, hsp[_s], _vsp);           \
        }                                                                   \
        const float _vx = _vxy.x, _vy = _vxy.y;                             \
        const float _vs = _vsp.x, _vp = _vsp.y;                             \
        const float _mxy = _vx * _vy;                                       \
        const float _mu2 = fmaf(_vx, _vx, _vy * _vy);                       \
        const float _A1 = fmaf(2.f, _mxy, C1F);                             \
        const float _A2 = fmaf(2.f, _vp - _mxy, C2F);                       \
        const float _B1 = _mu2 + C1F;                                       \
        const float _B2 = (_vs - _mu2) + C2F;                               \
        const float _ssim = (_A1 * _A2) * __builtin_amdgcn_rcpf(_B1 * _B2); \
        const float _dd = dring[((uu) + 6) % KW];  /* written step i-5 */   \
        const float _ch = __builtin_amdgcn_sqrtf(fmaf(_dd, _dd, EPS2));     \
        out[pbase + (oo) * IMG + col0 + lane] =                             \
            fmaf(0.3f, _ch, fmaf(2.0f, _dd * _dd, 0.6f * (1.f - _ssim)));   \
    } while (0)

    // ---- init prefetch: rows row0-5 (set0), row0-4 (set1) ----------------
    if (row0 > 0) { LOADR(0, row0 - 5); LOADR(1, row0 - 4); }

    // ---- prologue: steps i = 0..10 (u = i, set = i&1), r = row0-5+i ------
#define STEP_PRO(uu, ss) do {                                               \
        const bool _inr = (row0 - RAD + (uu)) >= 0;      /* wave-uniform */ \
        if (_inr) COMMITR(ss);                                              \
        if ((row0 - 3 + (uu)) >= 0) LOADR(ss, row0 - 3 + (uu));             \
        if (_inr) TAPS(uu); else ZERO_H(uu);                                \
    } while (0)

    STEP_PRO(0, 0); STEP_PRO(1, 1); STEP_PRO(2, 0); STEP_PRO(3, 1);
    STEP_PRO(4, 0); STEP_PRO(5, 1); STEP_PRO(6, 0); STEP_PRO(7, 1);
    STEP_PRO(8, 0); STEP_PRO(9, 1); STEP_PRO(10, 0);
    FINALIZE(10, row0);                    // first output row at i = 10

    // ---- block A: steps i = 11..21 (u = m, set = (m+1)&1), r = row0+6+m --
#define STEP_A(m, ss) do {                                                  \
        COMMITR(ss);                                                        \
        LOADR(ss, row0 + 8 + (m));                                          \
        TAPS(m);                                                            \
        FINALIZE(m, row0 + 1 + (m));                                        \
    } while (0)

    STEP_A(0, 1); STEP_A(1, 0); STEP_A(2, 1); STEP_A(3, 0); STEP_A(4, 1);
    STEP_A(5, 0); STEP_A(6, 1); STEP_A(7, 0); STEP_A(8, 1); STEP_A(9, 0);
    STEP_A(10, 1);
#undef STEP_A

    // ---- interior loop: j = 0,1; 22 steps each (i = 22+22j+t) ------------
    // u = t%11, set = t&1 (both literal); r = rbase+t; o = r-5.
    for (int j = 0; j < 2; ++j) {
        const int rbase = row0 + 17 + 22 * j;
#define STEP_I(t, uu, ss) do {                                              \
        COMMITR(ss);                                                        \
        LOADR(ss, rbase + (t) + 2);                                         \
        TAPS(uu);                                                           \
        FINALIZE(uu, rbase + (t) - 5);                                      \
    } while (0)
        STEP_I(0, 0, 0);   STEP_I(1, 1, 1);   STEP_I(2, 2, 0);
        STEP_I(3, 3, 1);   STEP_I(4, 4, 0);   STEP_I(5, 5, 1);
        STEP_I(6, 6, 0);   STEP_I(7, 7, 1);   STEP_I(8, 8, 0);
        STEP_I(9, 9, 1);   STEP_I(10, 10, 0); STEP_I(11, 0, 1);
        STEP_I(12, 1, 0);  STEP_I(13, 2, 1);  STEP_I(14, 3, 0);
        STEP_I(15, 4, 1);  STEP_I(16, 5, 0);  STEP_I(17, 6, 1);
        STEP_I(18, 7, 0);  STEP_I(19, 8, 1);  STEP_I(20, 9, 0);
        STEP_I(21, 10, 1);
#undef STEP_I
    }

    // ---- epilogue: steps i = 66..73 (u = m, set = m&1), r = row0+61+m ----
#define STEP_E(m, ss) do {                                                  \
        const bool _inr = (row0 + 61 + (m)) < IMG;       /* wave-uniform */ \
        if (_inr) COMMITR(ss);                                              \
        if (((m) < 6) && (row0 + 63 + (m)) < IMG)                           \
            LOADR(ss, row0 + 63 + (m));                                     \
        if (_inr) TAPS(m); else ZERO_H(m);                                  \
        FINALIZE(m, row0 + 56 + (m));                                       \
    } while (0)

    STEP_E(0, 0); STEP_E(1, 1); STEP_E(2, 0); STEP_E(3, 1);
    STEP_E(4, 0); STEP_E(5, 1); STEP_E(6, 0); STEP_E(7, 1);
#undef STEP_E
#undef STEP_PRO
#undef FINALIZE
#undef ZERO_H
#undef TAPS
#undef COMMITR
#undef LOADR
}

extern "C" void kernel_launch(void* const* d_in, const int* in_sizes, int n_in,
                              void* d_out, int out_size, void* d_ws, size_t ws_size,
                              hipStream_t stream) {
    const float* pred = (const float*)d_in[0];
    const float* target = (const float*)d_in[1];
    float* out = (float*)d_out;
    const int planes = in_sizes[0] / PLANE;     // 48

    // 64 waves per plane (8 strips x 8 tiles of 64 rows), 4 waves/block.
    dim3 grid(planes * 16);                     // 768 blocks = 3 per CU
    CombinedLossSSIMCharbMSE_81372450390186_kernel<<<grid, dim3(256), 0, stream>>>(
        pred, target, out);
}

// Round 7
// 211.082 us; speedup vs baseline: 1.0651x; 1.0651x over previous
//
#include <hip/hip_runtime.h>

// Fused separable 11x11 gaussian + SSIM/charb/MSE, wave-streaming form.
// R12: R10 schedule verbatim (STRH=64, 768 blocks = 3/CU, depth-2
// register prefetch, single LDS row buffer, launch_bounds(256,2)) plus
// ONLY the commit-site precompute from R11: COMMIT computes
// (x, y, x^2+y^2, x*y) once per element and stores float4 in LDS
// (ds_write_b128); TAPS is 11 ds_read_b128 + 44 scalar FMA. Rings and
// FINALIZE stay fully SCALAR -- R11's f32x2/float4 packed accumulators
// caused aligned-pair register fragmentation (VGPR 84->128 + 12MB spill
// despite the 256 budget; VALUBusy 69->23%). Same ring float count (44)
// scalar allocated fine at 84 VGPR in R10, so only the redundant-product
// cut (33 VALU/step) is kept, packed math abandoned.
// Static interior step ~150 -> ~122 VALU; predicted 72 -> 62-66us.
// Spill tripwire: VGPR must stay <=~100 and WRITE_SIZE == 49.2MB.
// Schedule: 11 prologue + 11 + 2x22 + 8 epilogue steps; ring index
// u=i%11 and prefetch-set parity i&1 literal everywhere; depth-2
// prefetch (COMMIT set i&1 loaded at step i-2, issue row r+2 into same
// set); boundary masking at commit-site so loads have no immediate
// consumer (stay in flight 2 full steps).
// Ring algebra: step i (u=i%11) -> h slot u; finalize at i>=10 emits row
// o=r-5 with weight GW[(u-s) mod 11] (GW symmetric); center diff
// dring[u] read 5 steps later at (u+6)%11. Out-of-range rows give h=0.

#define IMG    512
#define RAD    5
#define KW     11
#define STRH   64
#define ROWE   74                 // halo row entries (64 + 2*5)
#define PLANE  (IMG * IMG)

#define C1F  1e-4f
#define C2F  9e-4f
#define EPS2 1e-12f

#define W0 0.00102838f
#define W1 0.00759876f
#define W2 0.03600076f
#define W3 0.10936067f
#define W4 0.21300537f
#define W5 0.26601297f

__global__ __launch_bounds__(256, 2)
void CombinedLossSSIMCharbMSE_81372450390186_kernel(
    const float* __restrict__ pred,
    const float* __restrict__ target,
    float* __restrict__ out)
{
    const float GW[KW] = {W0, W1, W2, W3, W4, W5, W4, W3, W2, W1, W0};

    __shared__ float4 rbf[4 * ROWE];  // 4 waves x 1 float4 row, 4736 B

    const int lane = threadIdx.x & 63;
    const int wav  = threadIdx.x >> 6;
    const int wid  = (blockIdx.x << 2) | wav;   // global wave id
    const int plane = wid >> 6;                 // 64 waves per plane
    const int tile  = (wid >> 3) & 7;           // 8 row-tiles of 64
    const int strip = wid & 7;                  // 8 col-strips of 64
    const int col0 = strip << 6;
    const int row0 = tile << 6;
    const int pbase = plane * PLANE;

    // Column geometry (constant across rows). Entry e <-> col col0-5+e.
    const int  cA  = col0 - RAD + lane;         // entries 0..63
    const bool okA = (cA >= 0) & (cA < IMG);
    const int  cAc = min(max(cA, 0), IMG - 1);
    const int  cB  = col0 + 59 + lane;          // entries 64..73 (lanes 0..9)
    const bool okB = cB < IMG;
    const int  cBc = min(cB, IMG - 1);
    const bool doB = lane < 10;

    const int wb = wav * ROWE;                  // LDS row base (single buf)

    float hrx[KW], hry[KW], hrs[KW], hrp[KW], dring[KW];
#pragma unroll
    for (int s = 0; s < KW; ++s) {
        hrx[s] = 0.f; hry[s] = 0.f; hrs[s] = 0.f; hrp[s] = 0.f; dring[s] = 0.f;
    }

    // Two prefetch register sets (depth 2), ping-ponged by step parity.
    float pA0 = 0.f, tA0 = 0.f, pB0 = 0.f, tB0 = 0.f;
    float pA1 = 0.f, tA1 = 0.f, pB1 = 0.f, tB1 = 0.f;

#define LOADR(ss, rr) do {                                                  \
        const int _b = pbase + (rr) * IMG;                                  \
        pA##ss = pred[_b + cAc];                                            \
        tA##ss = target[_b + cAc];                                          \
        if (doB) {                                                          \
            pB##ss = pred[_b + cBc];                                        \
            tB##ss = target[_b + cBc];                                      \
        }                                                                   \
    } while (0)

    // Mask at commit; derive (s,p) from masked values (auto-zeroed OOB).
#define COMMITR(ss) do {                                                    \
        const float _mx = okA ? pA##ss : 0.f;                               \
        const float _my = okA ? tA##ss : 0.f;                               \
        float4 _v;                                                          \
        _v.x = _mx; _v.y = _my;                                             \
        _v.z = fmaf(_mx, _mx, _my * _my); _v.w = _mx * _my;                 \
        rbf[wb + lane] = _v;                                                \
        if (doB) {                                                          \
            const float _bx = okB ? pB##ss : 0.f;                           \
            const float _by = okB ? tB##ss : 0.f;                           \
            float4 _u;                                                      \
            _u.x = _bx; _u.y = _by;                                         \
            _u.z = fmaf(_bx, _bx, _by * _by); _u.w = _bx * _by;             \
            rbf[wb + 64 + lane] = _u;                                       \
        }                                                                   \
        __builtin_amdgcn_wave_barrier();  /* keep write->read order */      \
    } while (0)

#define TAPS(uu) do {                                                       \
        float _hx = 0.f, _hy = 0.f, _hs = 0.f, _hp = 0.f;                   \
        float _d5 = 0.f;                                                    \
        _Pragma("unroll")                                                   \
        for (int _d = 0; _d < KW; ++_d) {                                   \
            const float4 _t = rbf[wb + lane + _d];                          \
            if (_d == RAD) _d5 = _t.x - _t.y;                               \
            const float _w = GW[_d];                                        \
            _hx = fmaf(_w, _t.x, _hx);                                      \
            _hy = fmaf(_w, _t.y, _hy);                                      \
            _hs = fmaf(_w, _t.z, _hs);                                      \
            _hp = fmaf(_w, _t.w, _hp);                                      \
        }                                                                   \
        hrx[uu] = _hx; hry[uu] = _hy; hrs[uu] = _hs; hrp[uu] = _hp;         \
        dring[uu] = _d5;               /* center diff, used at step i+5 */  \
    } while (0)

#define ZERO_H(uu) do {                                                     \
        hrx[uu] = 0.f; hry[uu] = 0.f; hrs[uu] = 0.f; hrp[uu] = 0.f;         \
    } while (0)

#define FINALIZE(uu, oo) do {                                               \
        float _vx = 0.f, _vy = 0.f, _vs = 0.f, _vp = 0.f;                   \
        _Pragma("unroll")                                                   \
        for (int _s = 0; _s < KW; ++_s) {                                   \
            const float _w = GW[((uu) - _s + KW) % KW];                     \
            _vx = fmaf(_w, hrx[_s], _vx);                                   \
            _vy = fmaf(_w, hry[_s], _vy);                                   \
            _vs = fmaf(_w, hrs[_s], _vs);                                   \
            _vp = fmaf(_w, hrp[_s], _vp);                                   \
        }                                                                   \
        const float _mxy = _vx * _vy;                                       \
        const float _mu2 = fmaf(_vx, _vx, _vy * _vy);                       \
        const float _A1 = fmaf(2.f, _mxy, C1F);                             \
        const float _A2 = fmaf(2.f, _vp - _mxy, C2F);                       \
        const float _B1 = _mu2 + C1F;                                       \
        const float _B2 = (_vs - _mu2) + C2F;                               \
        const float _ssim = (_A1 * _A2) * __builtin_amdgcn_rcpf(_B1 * _B2); \
        const float _dd = dring[((uu) + 6) % KW];  /* written step i-5 */   \
        const float _ch = __builtin_amdgcn_sqrtf(fmaf(_dd, _dd, EPS2));     \
        out[pbase + (oo) * IMG + col0 + lane] =                             \
            fmaf(0.3f, _ch, fmaf(2.0f, _dd * _dd, 0.6f * (1.f - _ssim)));   \
    } while (0)

    // ---- init prefetch: rows row0-5 (set0), row0-4 (set1) ----------------
    if (row0 > 0) { LOADR(0, row0 - 5); LOADR(1, row0 - 4); }

    // ---- prologue: steps i = 0..10 (u = i, set = i&1), r = row0-5+i ------
#define STEP_PRO(uu, ss) do {                                               \
        const bool _inr = (row0 - RAD + (uu)) >= 0;      /* wave-uniform */ \
        if (_inr) COMMITR(ss);                                              \
        if ((row0 - 3 + (uu)) >= 0) LOADR(ss, row0 - 3 + (uu));             \
        if (_inr) TAPS(uu); else ZERO_H(uu);                                \
    } while (0)

    STEP_PRO(0, 0); STEP_PRO(1, 1); STEP_PRO(2, 0); STEP_PRO(3, 1);
    STEP_PRO(4, 0); STEP_PRO(5, 1); STEP_PRO(6, 0); STEP_PRO(7, 1);
    STEP_PRO(8, 0); STEP_PRO(9, 1); STEP_PRO(10, 0);
    FINALIZE(10, row0);                    // first output row at i = 10

    // ---- block A: steps i = 11..21 (u = m, set = (m+1)&1), r = row0+6+m --
#define STEP_A(m, ss) do {                                                  \
        COMMITR(ss);                                                        \
        LOADR(ss, row0 + 8 + (m));                                          \
        TAPS(m);                                                            \
        FINALIZE(m, row0 + 1 + (m));                                        \
    } while (0)

    STEP_A(0, 1); STEP_A(1, 0); STEP_A(2, 1); STEP_A(3, 0); STEP_A(4, 1);
    STEP_A(5, 0); STEP_A(6, 1); STEP_A(7, 0); STEP_A(8, 1); STEP_A(9, 0);
    STEP_A(10, 1);
#undef STEP_A

    // ---- interior loop: j = 0,1; 22 steps each (i = 22+22j+t) ------------
    // u = t%11, set = t&1 (both literal); r = rbase+t; o = r-5.
    for (int j = 0; j < 2; ++j) {
        const int rbase = row0 + 17 + 22 * j;
#define STEP_I(t, uu, ss) do {                                              \
        COMMITR(ss);                                                        \
        LOADR(ss, rbase + (t) + 2);                                         \
        TAPS(uu);                                                           \
        FINALIZE(uu, rbase + (t) - 5);                                      \
    } while (0)
        STEP_I(0, 0, 0);   STEP_I(1, 1, 1);   STEP_I(2, 2, 0);
        STEP_I(3, 3, 1);   STEP_I(4, 4, 0);   STEP_I(5, 5, 1);
        STEP_I(6, 6, 0);   STEP_I(7, 7, 1);   STEP_I(8, 8, 0);
        STEP_I(9, 9, 1);   STEP_I(10, 10, 0); STEP_I(11, 0, 1);
        STEP_I(12, 1, 0);  STEP_I(13, 2, 1);  STEP_I(14, 3, 0);
        STEP_I(15, 4, 1);  STEP_I(16, 5, 0);  STEP_I(17, 6, 1);
        STEP_I(18, 7, 0);  STEP_I(19, 8, 1);  STEP_I(20, 9, 0);
        STEP_I(21, 10, 1);
#undef STEP_I
    }

    // ---- epilogue: steps i = 66..73 (u = m, set = m&1), r = row0+61+m ----
#define STEP_E(m, ss) do {                                                  \
        const bool _inr = (row0 + 61 + (m)) < IMG;       /* wave-uniform */ \
        if (_inr) COMMITR(ss);                                              \
        if (((m) < 6) && (row0 + 63 + (m)) < IMG)                           \
            LOADR(ss, row0 + 63 + (m));                                     \
        if (_inr) TAPS(m); else ZERO_H(m);                                  \
        FINALIZE(m, row0 + 56 + (m));                                       \
    } while (0)

    STEP_E(0, 0); STEP_E(1, 1); STEP_E(2, 0); STEP_E(3, 1);
    STEP_E(4, 0); STEP_E(5, 1); STEP_E(6, 0); STEP_E(7, 1);
#undef STEP_E
#undef STEP_PRO
#undef FINALIZE
#undef ZERO_H
#undef TAPS
#undef COMMITR
#undef LOADR
}

extern "C" void kernel_launch(void* const* d_in, const int* in_sizes, int n_in,
                              void* d_out, int out_size, void* d_ws, size_t ws_size,
                              hipStream_t stream) {
    const float* pred = (const float*)d_in[0];
    const float* target = (const float*)d_in[1];
    float* out = (float*)d_out;
    const int planes = in_sizes[0] / PLANE;     // 48

    // 64 waves per plane (8 strips x 8 tiles of 64 rows), 4 waves/block.
    dim3 grid(planes * 16);                     // 768 blocks = 3 per CU
    CombinedLossSSIMCharbMSE_81372450390186_kernel<<<grid, dim3(256), 0, stream>>>(
        pred, target, out);
}

// Round 8
// 194.130 us; speedup vs baseline: 1.1581x; 1.0873x over previous
//
#include <hip/hip_runtime.h>

// Fused separable 11x11 gaussian + SSIM/charb/MSE, wave-streaming form.
// R13: R10 (72us: STRH=64, 3 blocks/CU, depth-2 prefetch, scalar rings,
// launch_bounds(256,2)) + restored DOUBLE-BUFFERED LDS row with the step
// reordered to decouple the LDS write from the reads:
//   TAPS(buf q) -> COMMIT(set q -> buf q^1) -> LOADR(set q, r+3) -> FINALIZE
// R10 wrote row r and read it back in the SAME step (single buffer):
// cross-lane overlapping addresses -> lgkmcnt drain of the write before
// the first tap FMA, every step (~100-200cy serial, waves convoy so TLP
// can't cover it). Now the write lands a full step (~600cy) before its
// reader. Global-load flight stays 2 steps (LOADR at step i feeds the
// COMMIT at step i+2; same set parity since commit-set = i&1 = load-set).
// R11/R12 lesson kept: NO float4 LDS (b128 quad temps spill at 128 VGPR;
// and precompute doubles LDS tap bytes - wrong direction, LDS pipe is
// co-critical with VALU at ~530-790cy vs 537cy per step-slot).
// Rows clamped to [0,511] at load; commits unconditional (garbage rows
// never read: TAPS guarded by r-in-range, else ZERO_H = zero padding).
// Ring algebra: step i (u=i%11) -> h slot u; finalize at i>=10 emits row
// o=r-5 with weight GW[(u-s) mod 11] (GW symmetric); center diff
// dring[u] read 5 steps later at (u+6)%11.

#define IMG    512
#define RAD    5
#define KW     11
#define STRH   64
#define ROWE   74                 // halo row entries (64 + 2*5)
#define PLANE  (IMG * IMG)

#define C1F  1e-4f
#define C2F  9e-4f
#define EPS2 1e-12f

#define W0 0.00102838f
#define W1 0.00759876f
#define W2 0.03600076f
#define W3 0.10936067f
#define W4 0.21300537f
#define W5 0.26601297f

__global__ __launch_bounds__(256, 2)
void CombinedLossSSIMCharbMSE_81372450390186_kernel(
    const float* __restrict__ pred,
    const float* __restrict__ target,
    float* __restrict__ out)
{
    const float GW[KW] = {W0, W1, W2, W3, W4, W5, W4, W3, W2, W1, W0};

    __shared__ float2 rb[8 * ROWE];   // 4 waves x 2 row buffers, 4736 B

    const int lane = threadIdx.x & 63;
    const int wav  = threadIdx.x >> 6;
    const int wid  = (blockIdx.x << 2) | wav;   // global wave id
    const int plane = wid >> 6;                 // 64 waves per plane
    const int tile  = (wid >> 3) & 7;           // 8 row-tiles of 64
    const int strip = wid & 7;                  // 8 col-strips of 64
    const int col0 = strip << 6;
    const int row0 = tile << 6;
    const int pbase = plane * PLANE;

    // Column geometry (constant across rows). Entry e <-> col col0-5+e.
    const int  cA  = col0 - RAD + lane;         // entries 0..63
    const bool okA = (cA >= 0) & (cA < IMG);
    const int  cAc = min(max(cA, 0), IMG - 1);
    const int  cB  = col0 + 59 + lane;          // entries 64..73 (lanes 0..9)
    const bool okB = cB < IMG;
    const int  cBc = min(cB, IMG - 1);
    const bool doB = lane < 10;

    // Hoisted per-buffer LDS pointers (lane folded in).
    float2* const b0 = &rb[((wav << 1) | 0) * ROWE] + lane;
    float2* const b1 = &rb[((wav << 1) | 1) * ROWE] + lane;

    float hrx[KW], hry[KW], hrs[KW], hrp[KW], dring[KW];
#pragma unroll
    for (int s = 0; s < KW; ++s) {
        hrx[s] = 0.f; hry[s] = 0.f; hrs[s] = 0.f; hrp[s] = 0.f; dring[s] = 0.f;
    }

    // Two prefetch register sets, ping-ponged by step parity.
    float pA0 = 0.f, tA0 = 0.f, pB0 = 0.f, tB0 = 0.f;
    float pA1 = 0.f, tA1 = 0.f, pB1 = 0.f, tB1 = 0.f;

#define LOADR(ss, rr) do {                                                  \
        const int _r = min(max((rr), 0), IMG - 1);   /* clamp: always ok */ \
        const int _b = pbase + _r * IMG;                                    \
        pA##ss = pred[_b + cAc];                                            \
        tA##ss = target[_b + cAc];                                          \
        if (doB) {                                                          \
            pB##ss = pred[_b + cBc];                                        \
            tB##ss = target[_b + cBc];                                      \
        }                                                                   \
    } while (0)

    // Commit set ss into buffer qb (0/1 literal). Mask columns here.
#define COMMITB(ss, qb) do {                                                \
        float2* _wp = (qb) ? b1 : b0;                                       \
        _wp[0] = make_float2(okA ? pA##ss : 0.f, okA ? tA##ss : 0.f);       \
        if (doB)                                                            \
            _wp[64] = make_float2(okB ? pB##ss : 0.f, okB ? tB##ss : 0.f);  \
        __builtin_amdgcn_wave_barrier();  /* pin write before next reads */ \
    } while (0)

#define TAPS(uu, qb) do {                                                   \
        const float2* _rp = (qb) ? b1 : b0;                                 \
        float _hx = 0.f, _hy = 0.f, _hs = 0.f, _hp = 0.f;                   \
        float2 _c5 = make_float2(0.f, 0.f);                                 \
        _Pragma("unroll")                                                   \
        for (int _d = 0; _d < KW; ++_d) {                                   \
            const float2 _t = _rp[_d];                                      \
            if (_d == RAD) _c5 = _t;                                        \
            const float _w = GW[_d];                                        \
            _hx = fmaf(_w, _t.x, _hx);                                      \
            _hy = fmaf(_w, _t.y, _hy);                                      \
            _hs = fmaf(_w, fmaf(_t.x, _t.x, _t.y * _t.y), _hs);             \
            _hp = fmaf(_w, _t.x * _t.y, _hp);                               \
        }                                                                   \
        hrx[uu] = _hx; hry[uu] = _hy; hrs[uu] = _hs; hrp[uu] = _hp;         \
        dring[uu] = _c5.x - _c5.y;     /* center diff, used at step i+5 */  \
    } while (0)

#define ZERO_H(uu) do {                                                     \
        hrx[uu] = 0.f; hry[uu] = 0.f; hrs[uu] = 0.f; hrp[uu] = 0.f;         \
    } while (0)

#define FINALIZE(uu, oo) do {                                               \
        float _vx = 0.f, _vy = 0.f, _vs = 0.f, _vp = 0.f;                   \
        _Pragma("unroll")                                                   \
        for (int _s = 0; _s < KW; ++_s) {                                   \
            const float _w = GW[((uu) - _s + KW) % KW];                     \
            _vx = fmaf(_w, hrx[_s], _vx);                                   \
            _vy = fmaf(_w, hry[_s], _vy);                                   \
            _vs = fmaf(_w, hrs[_s], _vs);                                   \
            _vp = fmaf(_w, hrp[_s], _vp);                                   \
        }                                                                   \
        const float _mxy = _vx * _vy;                                       \
        const float _mu2 = fmaf(_vx, _vx, _vy * _vy);                       \
        const float _A1 = fmaf(2.f, _mxy, C1F);                             \
        const float _A2 = fmaf(2.f, _vp - _mxy, C2F);                       \
        const float _B1 = _mu2 + C1F;                                       \
        const float _B2 = (_vs - _mu2) + C2F;                               \
        const float _ssim = (_A1 * _A2) * __builtin_amdgcn_rcpf(_B1 * _B2); \
        const float _dd = dring[((uu) + 6) % KW];  /* written step i-5 */   \
        const float _ch = __builtin_amdgcn_sqrtf(fmaf(_dd, _dd, EPS2));     \
        out[pbase + (oo) * IMG + col0 + lane] =                             \
            fmaf(0.3f, _ch, fmaf(2.0f, _dd * _dd, 0.6f * (1.f - _ssim)));   \
    } while (0)

    // ---- pre-loop: buf0 <- row row0-5; sets hold rows row0-4, row0-3 -----
    LOADR(1, row0 - 5);
    COMMITB(1, 0);                    // pre-commit (garbage-ok if row0==0:
                                      // only read at step 0 where r<0 -> ZERO_H)
    LOADR(0, row0 - 4);               // committed at step 0 -> buf1
    LOADR(1, row0 - 3);               // committed at step 1 -> buf0

    // Per step i (q=i&1): TAPS(buf q) | COMMIT(set q -> buf q^1, row r+1)
    //                     | LOADR(set q, row r+3) | FINALIZE (i>=10)
    // ---- prologue: steps i = 0..10 (u = i, q = i&1), r = row0-5+i --------
#define STEP_PRO(uu, qq) do {                                               \
        const bool _inr = (row0 - RAD + (uu)) >= 0;      /* wave-uniform */ \
        if (_inr) TAPS(uu, qq); else ZERO_H(uu);                            \
        COMMITB(qq, (qq) ^ 1);                                              \
        LOADR(qq, row0 - 2 + (uu));                                         \
    } while (0)

    STEP_PRO(0, 0); STEP_PRO(1, 1); STEP_PRO(2, 0); STEP_PRO(3, 1);
    STEP_PRO(4, 0); STEP_PRO(5, 1); STEP_PRO(6, 0); STEP_PRO(7, 1);
    STEP_PRO(8, 0); STEP_PRO(9, 1); STEP_PRO(10, 0);
    FINALIZE(10, row0);                    // first output row at i = 10

    // ---- block A: steps i = 11..21 (u = m, q = (m+1)&1), r = row0+6+m ----
#define STEP_A(m, qq) do {                                                  \
        TAPS(m, qq);                                                        \
        COMMITB(qq, (qq) ^ 1);                                              \
        LOADR(qq, row0 + 9 + (m));                                          \
        FINALIZE(m, row0 + 1 + (m));                                        \
    } while (0)

    STEP_A(0, 1); STEP_A(1, 0); STEP_A(2, 1); STEP_A(3, 0); STEP_A(4, 1);
    STEP_A(5, 0); STEP_A(6, 1); STEP_A(7, 0); STEP_A(8, 1); STEP_A(9, 0);
    STEP_A(10, 1);
#undef STEP_A

    // ---- interior loop: j = 0,1; 22 steps each (i = 22+22j+t) ------------
    // u = t%11, q = t&1 (both literal); r = rbase+t; o = r-5.
    for (int j = 0; j < 2; ++j) {
        const int rbase = row0 + 17 + 22 * j;
#define STEP_I(t, uu, qq) do {                                              \
        TAPS(uu, qq);                                                       \
        COMMITB(qq, (qq) ^ 1);                                              \
        LOADR(qq, rbase + (t) + 3);                                         \
        FINALIZE(uu, rbase + (t) - 5);                                      \
    } while (0)
        STEP_I(0, 0, 0);   STEP_I(1, 1, 1);   STEP_I(2, 2, 0);
        STEP_I(3, 3, 1);   STEP_I(4, 4, 0);   STEP_I(5, 5, 1);
        STEP_I(6, 6, 0);   STEP_I(7, 7, 1);   STEP_I(8, 8, 0);
        STEP_I(9, 9, 1);   STEP_I(10, 10, 0); STEP_I(11, 0, 1);
        STEP_I(12, 1, 0);  STEP_I(13, 2, 1);  STEP_I(14, 3, 0);
        STEP_I(15, 4, 1);  STEP_I(16, 5, 0);  STEP_I(17, 6, 1);
        STEP_I(18, 7, 0);  STEP_I(19, 8, 1);  STEP_I(20, 9, 0);
        STEP_I(21, 10, 1);
#undef STEP_I
    }

    // ---- epilogue: steps i = 66..73 (u = m, q = m&1), r = row0+61+m ------
#define STEP_E(m, qq) do {                                                  \
        const bool _inr = (row0 + 61 + (m)) < IMG;       /* wave-uniform */ \
        if (_inr) TAPS(m, qq); else ZERO_H(m);                              \
        COMMITB(qq, (qq) ^ 1);                                              \
        LOADR(qq, row0 + 64 + (m));                                         \
        FINALIZE(m, row0 + 56 + (m));                                       \
    } while (0)

    STEP_E(0, 0); STEP_E(1, 1); STEP_E(2, 0); STEP_E(3, 1);
    STEP_E(4, 0); STEP_E(5, 1); STEP_E(6, 0); STEP_E(7, 1);
#undef STEP_E
#undef STEP_PRO
#undef FINALIZE
#undef ZERO_H
#undef TAPS
#undef COMMITB
#undef LOADR
}

extern "C" void kernel_launch(void* const* d_in, const int* in_sizes, int n_in,
                              void* d_out, int out_size, void* d_ws, size_t ws_size,
                              hipStream_t stream) {
    const float* pred = (const float*)d_in[0];
    const float* target = (const float*)d_in[1];
    float* out = (float*)d_out;
    const int planes = in_sizes[0] / PLANE;     // 48

    // 64 waves per plane (8 strips x 8 tiles of 64 rows), 4 waves/block.
    dim3 grid(planes * 16);                     // 768 blocks = 3 per CU
    CombinedLossSSIMCharbMSE_81372450390186_kernel<<<grid, dim3(256), 0, stream>>>(
        pred, target, out);
}

// Round 9
// 171.752 us; speedup vs baseline: 1.3090x; 1.1303x over previous
//
#include <hip/hip_runtime.h>
#include <hip/hip_fp16.h>

// Fused separable 11x11 gaussian + SSIM/charb/MSE, wave-streaming form.
// R14: R10 schedule VERBATIM (72us best: STRH=64, 768 blocks = 3/CU,
// depth-2 register prefetch, single LDS row buffer, step order
// COMMIT -> LOADR -> TAPS -> FINALIZE, literal ring/set indices,
// launch_bounds(256,2)) with two macro-body-only changes:
// 1) FP16 LDS row: store half2(x,y) (4B/entry, was float2 8B). Halves
//    the dominant LDS segment (tap reads 5.6KB -> 2.8KB per wave-step).
//    Global loads/prefetch/rings/all math stay fp32; only the staged
//    row is quantized (~2^-12 on [0,1) inputs -> ~3e-3 loss error).
// 2) pk-paired tap accumulators in LOCALS (f32x2 axy, asq) via
//    __builtin_elementwise_fma -> v_pk_fma_f32. Pays for the 2 cvt/tap
//    fp16 unpack; net VALU/step ~= R10+5. NOT arrays (R11's spill was
//    vector-typed RINGS; R12's was 11 live b128 quads - locals are 2
//    aligned pairs, consumed per-tap).
// R13 post-mortem: TAPS-first reorder added ~30us stall (loads issued
// late, step begins with dependent ds_reads) - R10's order restored.
// R10 pipe model: 778cy/step-slot = VALU 537 (69%) + LDS 580-780
// co-critical serialization; this round shrinks the LDS segment 2x.
// Tripwires: WRITE_SIZE must stay 49.2MB (spill), absmax <= ~0.03
// (fp16); if passed:false -> revert fp16 half only next round.
// Ring algebra: step i (u=i%11) -> h slot u; finalize at i>=10 emits row
// o=r-5 with weight GW[(u-s) mod 11] (GW symmetric); center diff
// dring[u] read 5 steps later at (u+6)%11. Out-of-range rows give h=0.

#define IMG    512
#define RAD    5
#define KW     11
#define STRH   64
#define ROWE   74                 // halo row entries (64 + 2*5)
#define PLANE  (IMG * IMG)

#define C1F  1e-4f
#define C2F  9e-4f
#define EPS2 1e-12f

#define W0 0.00102838f
#define W1 0.00759876f
#define W2 0.03600076f
#define W3 0.10936067f
#define W4 0.21300537f
#define W5 0.26601297f

typedef float f32x2 __attribute__((ext_vector_type(2)));

__global__ __launch_bounds__(256, 2)
void CombinedLossSSIMCharbMSE_81372450390186_kernel(
    const float* __restrict__ pred,
    const float* __restrict__ target,
    float* __restrict__ out)
{
    const float GW[KW] = {W0, W1, W2, W3, W4, W5, W4, W3, W2, W1, W0};

    __shared__ __half2 rb[4 * ROWE];  // 4 waves x 1 half2 row, 1184 B

    const int lane = threadIdx.x & 63;
    const int wav  = threadIdx.x >> 6;
    const int wid  = (blockIdx.x << 2) | wav;   // global wave id
    const int plane = wid >> 6;                 // 64 waves per plane
    const int tile  = (wid >> 3) & 7;           // 8 row-tiles of 64
    const int strip = wid & 7;                  // 8 col-strips of 64
    const int col0 = strip << 6;
    const int row0 = tile << 6;
    const int pbase = plane * PLANE;

    // Column geometry (constant across rows). Entry e <-> col col0-5+e.
    const int  cA  = col0 - RAD + lane;         // entries 0..63
    const bool okA = (cA >= 0) & (cA < IMG);
    const int  cAc = min(max(cA, 0), IMG - 1);
    const int  cB  = col0 + 59 + lane;          // entries 64..73 (lanes 0..9)
    const bool okB = cB < IMG;
    const int  cBc = min(cB, IMG - 1);
    const bool doB = lane < 10;

    const int wb = wav * ROWE;                  // LDS row base (single buf)

    float hrx[KW], hry[KW], hrs[KW], hrp[KW], dring[KW];
#pragma unroll
    for (int s = 0; s < KW; ++s) {
        hrx[s] = 0.f; hry[s] = 0.f; hrs[s] = 0.f; hrp[s] = 0.f; dring[s] = 0.f;
    }

    // Two prefetch register sets (depth 2), ping-ponged by step parity.
    float pA0 = 0.f, tA0 = 0.f, pB0 = 0.f, tB0 = 0.f;
    float pA1 = 0.f, tA1 = 0.f, pB1 = 0.f, tB1 = 0.f;

#define LOADR(ss, rr) do {                                                  \
        const int _b = pbase + (rr) * IMG;                                  \
        pA##ss = pred[_b + cAc];                                            \
        tA##ss = target[_b + cAc];                                          \
        if (doB) {                                                          \
            pB##ss = pred[_b + cBc];                                        \
            tB##ss = target[_b + cBc];                                      \
        }                                                                   \
    } while (0)

    // Mask at commit; pack to half2 (RNE) for the staged row.
#define COMMITR(ss) do {                                                    \
        const float _mx = okA ? pA##ss : 0.f;                               \
        const float _my = okA ? tA##ss : 0.f;                               \
        rb[wb + lane] = __floats2half2_rn(_mx, _my);                        \
        if (doB) {                                                          \
            const float _bx = okB ? pB##ss : 0.f;                           \
            const float _by = okB ? tB##ss : 0.f;                           \
            rb[wb + 64 + lane] = __floats2half2_rn(_bx, _by);               \
        }                                                                   \
        __builtin_amdgcn_wave_barrier();  /* keep write->read order */      \
    } while (0)

#define TAPS(uu) do {                                                       \
        f32x2 _axy = (f32x2){0.f, 0.f};                                     \
        f32x2 _asq = (f32x2){0.f, 0.f};                                     \
        float _hp = 0.f, _d5 = 0.f;                                         \
        _Pragma("unroll")                                                   \
        for (int _d = 0; _d < KW; ++_d) {                                   \
            const float2 _t = __half22float2(rb[wb + lane + _d]);           \
            if (_d == RAD) _d5 = _t.x - _t.y;                               \
            const f32x2 _wp2 = {GW[_d], GW[_d]};                            \
            const f32x2 _tv = {_t.x, _t.y};                                 \
            _axy = __builtin_elementwise_fma(_wp2, _tv, _axy);              \
            _asq = __builtin_elementwise_fma(_wp2, _tv * _tv, _asq);        \
            _hp = fmaf(GW[_d], _t.x * _t.y, _hp);                           \
        }                                                                   \
        hrx[uu] = _axy.x; hry[uu] = _axy.y;                                 \
        hrs[uu] = _asq.x + _asq.y; hrp[uu] = _hp;                           \
        dring[uu] = _d5;               /* center diff, used at step i+5 */  \
    } while (0)

#define ZERO_H(uu) do {                                                     \
        hrx[uu] = 0.f; hry[uu] = 0.f; hrs[uu] = 0.f; hrp[uu] = 0.f;         \
    } while (0)

#define FINALIZE(uu, oo) do {                                               \
        float _vx = 0.f, _vy = 0.f, _vs = 0.f, _vp = 0.f;                   \
        _Pragma("unroll")                                                   \
        for (int _s = 0; _s < KW; ++_s) {                                   \
            const float _w = GW[((uu) - _s + KW) % KW];                     \
            _vx = fmaf(_w, hrx[_s], _vx);                                   \
            _vy = fmaf(_w, hry[_s], _vy);                                   \
            _vs = fmaf(_w, hrs[_s], _vs);                                   \
            _vp = fmaf(_w, hrp[_s], _vp);                                   \
        }                                                                   \
        const float _mxy = _vx * _vy;                                       \
        const float _mu2 = fmaf(_vx, _vx, _vy * _vy);                       \
        const float _A1 = fmaf(2.f, _mxy, C1F);                             \
        const float _A2 = fmaf(2.f, _vp - _mxy, C2F);                       \
        const float _B1 = _mu2 + C1F;                                       \
        const float _B2 = (_vs - _mu2) + C2F;                               \
        const float _ssim = (_A1 * _A2) * __builtin_amdgcn_rcpf(_B1 * _B2); \
        const float _dd = dring[((uu) + 6) % KW];  /* written step i-5 */   \
        const float _ch = __builtin_amdgcn_sqrtf(fmaf(_dd, _dd, EPS2));     \
        out[pbase + (oo) * IMG + col0 + lane] =                             \
            fmaf(0.3f, _ch, fmaf(2.0f, _dd * _dd, 0.6f * (1.f - _ssim)));   \
    } while (0)

    // ---- init prefetch: rows row0-5 (set0), row0-4 (set1) ----------------
    if (row0 > 0) { LOADR(0, row0 - 5); LOADR(1, row0 - 4); }

    // ---- prologue: steps i = 0..10 (u = i, set = i&1), r = row0-5+i ------
#define STEP_PRO(uu, ss) do {                                               \
        const bool _inr = (row0 - RAD + (uu)) >= 0;      /* wave-uniform */ \
        if (_inr) COMMITR(ss);                                              \
        if ((row0 - 3 + (uu)) >= 0) LOADR(ss, row0 - 3 + (uu));             \
        if (_inr) TAPS(uu); else ZERO_H(uu);                                \
    } while (0)

    STEP_PRO(0, 0); STEP_PRO(1, 1); STEP_PRO(2, 0); STEP_PRO(3, 1);
    STEP_PRO(4, 0); STEP_PRO(5, 1); STEP_PRO(6, 0); STEP_PRO(7, 1);
    STEP_PRO(8, 0); STEP_PRO(9, 1); STEP_PRO(10, 0);
    FINALIZE(10, row0);                    // first output row at i = 10

    // ---- block A: steps i = 11..21 (u = m, set = (m+1)&1), r = row0+6+m --
#define STEP_A(m, ss) do {                                                  \
        COMMITR(ss);                                                        \
        LOADR(ss, row0 + 8 + (m));                                          \
        TAPS(m);                                                            \
        FINALIZE(m, row0 + 1 + (m));                                        \
    } while (0)

    STEP_A(0, 1); STEP_A(1, 0); STEP_A(2, 1); STEP_A(3, 0); STEP_A(4, 1);
    STEP_A(5, 0); STEP_A(6, 1); STEP_A(7, 0); STEP_A(8, 1); STEP_A(9, 0);
    STEP_A(10, 1);
#undef STEP_A

    // ---- interior loop: j = 0,1; 22 steps each (i = 22+22j+t) ------------
    // u = t%11, set = t&1 (both literal); r = rbase+t; o = r-5.
    for (int j = 0; j < 2; ++j) {
        const int rbase = row0 + 17 + 22 * j;
#define STEP_I(t, uu, ss) do {                                              \
        COMMITR(ss);                                                        \
        LOADR(ss, rbase + (t) + 2);                                         \
        TAPS(uu);                                                           \
        FINALIZE(uu, rbase + (t) - 5);                                      \
    } while (0)
        STEP_I(0, 0, 0);   STEP_I(1, 1, 1);   STEP_I(2, 2, 0);
        STEP_I(3, 3, 1);   STEP_I(4, 4, 0);   STEP_I(5, 5, 1);
        STEP_I(6, 6, 0);   STEP_I(7, 7, 1);   STEP_I(8, 8, 0);
        STEP_I(9, 9, 1);   STEP_I(10, 10, 0); STEP_I(11, 0, 1);
        STEP_I(12, 1, 0);  STEP_I(13, 2, 1);  STEP_I(14, 3, 0);
        STEP_I(15, 4, 1);  STEP_I(16, 5, 0);  STEP_I(17, 6, 1);
        STEP_I(18, 7, 0);  STEP_I(19, 8, 1);  STEP_I(20, 9, 0);
        STEP_I(21, 10, 1);
#undef STEP_I
    }

    // ---- epilogue: steps i = 66..73 (u = m, set = m&1), r = row0+61+m ----
#define STEP_E(m, ss) do {                                                  \
        const bool _inr = (row0 + 61 + (m)) < IMG;       /* wave-uniform */ \
        if (_inr) COMMITR(ss);                                              \
        if (((m) < 6) && (row0 + 63 + (m)) < IMG)                           \
            LOADR(ss, row0 + 63 + (m));                                     \
        if (_inr) TAPS(m); else ZERO_H(m);                                  \
        FINALIZE(m, row0 + 56 + (m));                                       \
    } while (0)

    STEP_E(0, 0); STEP_E(1, 1); STEP_E(2, 0); STEP_E(3, 1);
    STEP_E(4, 0); STEP_E(5, 1); STEP_E(6, 0); STEP_E(7, 1);
#undef STEP_E
#undef STEP_PRO
#undef FINALIZE
#undef ZERO_H
#undef TAPS
#undef COMMITR
#undef LOADR
}

extern "C" void kernel_launch(void* const* d_in, const int* in_sizes, int n_in,
                              void* d_out, int out_size, void* d_ws, size_t ws_size,
                              hipStream_t stream) {
    const float* pred = (const float*)d_in[0];
    const float* target = (const float*)d_in[1];
    float* out = (float*)d_out;
    const int planes = in_sizes[0] / PLANE;     // 48

    // 64 waves per plane (8 strips x 8 tiles of 64 rows), 4 waves/block.
    dim3 grid(planes * 16);                     // 768 blocks = 3 per CU
    CombinedLossSSIMCharbMSE_81372450390186_kernel<<<grid, dim3(256), 0, stream>>>(
        pred, target, out);
}

// Round 10
// 162.917 us; speedup vs baseline: 1.3800x; 1.0542x over previous
//
#include <hip/hip_runtime.h>

// Fused separable 11x11 gaussian + SSIM/charb/MSE, wave-streaming form.
// R15: R10 VERBATIM (72us best: STRH=64, 768 blocks = 3/CU, depth-2
// register prefetch, single LDS row buffer, COMMIT -> LOADR -> TAPS ->
// FINALIZE, literal ring/set indices, launch_bounds(256,2)) + ONE change:
// readfirstlane on the wave-id so every address root is SGPR.
// R10 audit: 268 VALU instr/wave-step measured vs ~150 static arithmetic.
// The gap is addressing: pbase/row0/col0/wb derive from wav=threadIdx>>6,
// which LLVM divergence analysis marks divergent -> all global load/store
// addresses materialize as per-lane 64-bit VALU chains every step.
// These are provably wave-uniform; __builtin_amdgcn_readfirstlane(wid)
// makes them SGPR (HipKittens technique: readfirstlane-hoist bases),
// turning loads into s[base]+v_laneoff form with SALU row bumps.
// R14 lesson (reverted): LDS cost is per-INSTRUCTION not per-byte; fp16
// staging added cvt VALU for zero LDS gain (81us). R12/R11: float4/packed
// rings spill. R13: TAPS-first order stalls loads. R10 structure stands.
// Ring algebra: step i (u=i%11) -> h slot u; finalize at i>=10 emits row
// o=r-5 with weight GW[(u-s) mod 11] (GW symmetric); center diff
// dring[u] read 5 steps later at (u+6)%11. Out-of-range rows give h=0.

#define IMG    512
#define RAD    5
#define KW     11
#define STRH   64
#define ROWE   74                 // halo row entries (64 + 2*5)
#define PLANE  (IMG * IMG)

#define C1F  1e-4f
#define C2F  9e-4f
#define EPS2 1e-12f

#define W0 0.00102838f
#define W1 0.00759876f
#define W2 0.03600076f
#define W3 0.10936067f
#define W4 0.21300537f
#define W5 0.26601297f

__global__ __launch_bounds__(256, 2)
void CombinedLossSSIMCharbMSE_81372450390186_kernel(
    const float* __restrict__ pred,
    const float* __restrict__ target,
    float* __restrict__ out)
{
    const float GW[KW] = {W0, W1, W2, W3, W4, W5, W4, W3, W2, W1, W0};

    __shared__ float2 rb[4 * ROWE];   // 4 waves x 1 row buffer, 2368 B

    const int lane = threadIdx.x & 63;
    // Wave id, forced into an SGPR: everything derived below is uniform.
    const int wid = __builtin_amdgcn_readfirstlane(
        (int)((blockIdx.x << 2) | (threadIdx.x >> 6)));
    const int wav   = wid & 3;                  // wave slot in block (SGPR)
    const int plane = wid >> 6;                 // 64 waves per plane
    const int tile  = (wid >> 3) & 7;           // 8 row-tiles of 64
    const int strip = wid & 7;                  // 8 col-strips of 64
    const int col0 = strip << 6;                // SGPR
    const int row0 = tile << 6;                 // SGPR
    const int pbase = plane * PLANE;            // SGPR

    // Column geometry (constant across rows). Entry e <-> col col0-5+e.
    const int  cA  = col0 - RAD + lane;         // entries 0..63 (VGPR)
    const bool okA = (cA >= 0) & (cA < IMG);
    const int  cAc = min(max(cA, 0), IMG - 1);
    const int  cB  = col0 + 59 + lane;          // entries 64..73 (lanes 0..9)
    const bool okB = cB < IMG;
    const int  cBc = min(cB, IMG - 1);
    const bool doB = lane < 10;

    const int wb = wav * ROWE;                  // LDS row base (SGPR)

    float hrx[KW], hry[KW], hrs[KW], hrp[KW], dring[KW];
#pragma unroll
    for (int s = 0; s < KW; ++s) {
        hrx[s] = 0.f; hry[s] = 0.f; hrs[s] = 0.f; hrp[s] = 0.f; dring[s] = 0.f;
    }

    // Two prefetch register sets (depth 2), ping-ponged by step parity.
    float pA0 = 0.f, tA0 = 0.f, pB0 = 0.f, tB0 = 0.f;
    float pA1 = 0.f, tA1 = 0.f, pB1 = 0.f, tB1 = 0.f;

#define LOADR(ss, rr) do {                                                  \
        const int _b = pbase + (rr) * IMG;      /* SGPR arithmetic */       \
        pA##ss = pred[_b + cAc];                                            \
        tA##ss = target[_b + cAc];                                          \
        if (doB) {                                                          \
            pB##ss = pred[_b + cBc];                                        \
            tB##ss = target[_b + cBc];                                      \
        }                                                                   \
    } while (0)

    // Mask at commit (loads have no immediate consumer -> 2-step flight).
#define COMMITR(ss) do {                                                    \
        rb[wb + lane] =                                                     \
            make_float2(okA ? pA##ss : 0.f, okA ? tA##ss : 0.f);            \
        if (doB) rb[wb + 64 + lane] =                                       \
            make_float2(okB ? pB##ss : 0.f, okB ? tB##ss : 0.f);            \
        __builtin_amdgcn_wave_barrier();  /* keep write->read order */      \
    } while (0)

#define TAPS(uu) do {                                                       \
        float _hx = 0.f, _hy = 0.f, _hs = 0.f, _hp = 0.f;                   \
        float2 _c5 = make_float2(0.f, 0.f);                                 \
        _Pragma("unroll")                                                   \
        for (int _d = 0; _d < KW; ++_d) {                                   \
            const float2 _t = rb[wb + lane + _d];                           \
            if (_d == RAD) _c5 = _t;                                        \
            const float _w = GW[_d];                                        \
            _hx = fmaf(_w, _t.x, _hx);                                      \
            _hy = fmaf(_w, _t.y, _hy);                                      \
            _hs = fmaf(_w, fmaf(_t.x, _t.x, _t.y * _t.y), _hs);             \
            _hp = fmaf(_w, _t.x * _t.y, _hp);                               \
        }                                                                   \
        hrx[uu] = _hx; hry[uu] = _hy; hrs[uu] = _hs; hrp[uu] = _hp;         \
        dring[uu] = _c5.x - _c5.y;     /* center diff, used at step i+5 */  \
    } while (0)

#define ZERO_H(uu) do {                                                     \
        hrx[uu] = 0.f; hry[uu] = 0.f; hrs[uu] = 0.f; hrp[uu] = 0.f;         \
    } while (0)

#define FINALIZE(uu, oo) do {                                               \
        float _vx = 0.f, _vy = 0.f, _vs = 0.f, _vp = 0.f;                   \
        _Pragma("unroll")                                                   \
        for (int _s = 0; _s < KW; ++_s) {                                   \
            const float _w = GW[((uu) - _s + KW) % KW];                     \
            _vx = fmaf(_w, hrx[_s], _vx);                                   \
            _vy = fmaf(_w, hry[_s], _vy);                                   \
            _vs = fmaf(_w, hrs[_s], _vs);                                   \
            _vp = fmaf(_w, hrp[_s], _vp);                                   \
        }                                                                   \
        const float _mxy = _vx * _vy;                                       \
        const float _mu2 = fmaf(_vx, _vx, _vy * _vy);                       \
        const float _A1 = fmaf(2.f, _mxy, C1F);                             \
        const float _A2 = fmaf(2.f, _vp - _mxy, C2F);                       \
        const float _B1 = _mu2 + C1F;                                       \
        const float _B2 = (_vs - _mu2) + C2F;                               \
        const float _ssim = (_A1 * _A2) * __builtin_amdgcn_rcpf(_B1 * _B2); \
        const float _dd = dring[((uu) + 6) % KW];  /* written step i-5 */   \
        const float _ch = __builtin_amdgcn_sqrtf(fmaf(_dd, _dd, EPS2));     \
        out[pbase + (oo) * IMG + col0 + lane] =                             \
            fmaf(0.3f, _ch, fmaf(2.0f, _dd * _dd, 0.6f * (1.f - _ssim)));   \
    } while (0)

    // ---- init prefetch: rows row0-5 (set0), row0-4 (set1) ----------------
    if (row0 > 0) { LOADR(0, row0 - 5); LOADR(1, row0 - 4); }

    // ---- prologue: steps i = 0..10 (u = i, set = i&1), r = row0-5+i ------
#define STEP_PRO(uu, ss) do {                                               \
        const bool _inr = (row0 - RAD + (uu)) >= 0;      /* wave-uniform */ \
        if (_inr) COMMITR(ss);                                              \
        if ((row0 - 3 + (uu)) >= 0) LOADR(ss, row0 - 3 + (uu));             \
        if (_inr) TAPS(uu); else ZERO_H(uu);                                \
    } while (0)

    STEP_PRO(0, 0); STEP_PRO(1, 1); STEP_PRO(2, 0); STEP_PRO(3, 1);
    STEP_PRO(4, 0); STEP_PRO(5, 1); STEP_PRO(6, 0); STEP_PRO(7, 1);
    STEP_PRO(8, 0); STEP_PRO(9, 1); STEP_PRO(10, 0);
    FINALIZE(10, row0);                    // first output row at i = 10

    // ---- block A: steps i = 11..21 (u = m, set = (m+1)&1), r = row0+6+m --
#define STEP_A(m, ss) do {                                                  \
        COMMITR(ss);                                                        \
        LOADR(ss, row0 + 8 + (m));                                          \
        TAPS(m);                                                            \
        FINALIZE(m, row0 + 1 + (m));                                        \
    } while (0)

    STEP_A(0, 1); STEP_A(1, 0); STEP_A(2, 1); STEP_A(3, 0); STEP_A(4, 1);
    STEP_A(5, 0); STEP_A(6, 1); STEP_A(7, 0); STEP_A(8, 1); STEP_A(9, 0);
    STEP_A(10, 1);
#undef STEP_A

    // ---- interior loop: j = 0,1; 22 steps each (i = 22+22j+t) ------------
    // u = t%11, set = t&1 (both literal); r = rbase+t; o = r-5.
    for (int j = 0; j < 2; ++j) {
        const int rbase = row0 + 17 + 22 * j;
#define STEP_I(t, uu, ss) do {                                              \
        COMMITR(ss);                                                        \
        LOADR(ss, rbase + (t) + 2);                                         \
        TAPS(uu);                                                           \
        FINALIZE(uu, rbase + (t) - 5);                                      \
    } while (0)
        STEP_I(0, 0, 0);   STEP_I(1, 1, 1);   STEP_I(2, 2, 0);
        STEP_I(3, 3, 1);   STEP_I(4, 4, 0);   STEP_I(5, 5, 1);
        STEP_I(6, 6, 0);   STEP_I(7, 7, 1);   STEP_I(8, 8, 0);
        STEP_I(9, 9, 1);   STEP_I(10, 10, 0); STEP_I(11, 0, 1);
        STEP_I(12, 1, 0);  STEP_I(13, 2, 1);  STEP_I(14, 3, 0);
        STEP_I(15, 4, 1);  STEP_I(16, 5, 0);  STEP_I(17, 6, 1);
        STEP_I(18, 7, 0);  STEP_I(19, 8, 1);  STEP_I(20, 9, 0);
        STEP_I(21, 10, 1);
#undef STEP_I
    }

    // ---- epilogue: steps i = 66..73 (u = m, set = m&1), r = row0+61+m ----
#define STEP_E(m, ss) do {                                                  \
        const bool _inr = (row0 + 61 + (m)) < IMG;       /* wave-uniform */ \
        if (_inr) COMMITR(ss);                                              \
        if (((m) < 6) && (row0 + 63 + (m)) < IMG)                           \
            LOADR(ss, row0 + 63 + (m));                                     \
        if (_inr) TAPS(m); else ZERO_H(m);                                  \
        FINALIZE(m, row0 + 56 + (m));                                       \
    } while (0)

    STEP_E(0, 0); STEP_E(1, 1); STEP_E(2, 0); STEP_E(3, 1);
    STEP_E(4, 0); STEP_E(5, 1); STEP_E(6, 0); STEP_E(7, 1);
#undef STEP_E
#undef STEP_PRO
#undef FINALIZE
#undef ZERO_H
#undef TAPS
#undef COMMITR
#undef LOADR
}

extern "C" void kernel_launch(void* const* d_in, const int* in_sizes, int n_in,
                              void* d_out, int out_size, void* d_ws, size_t ws_size,
                              hipStream_t stream) {
    const float* pred = (const float*)d_in[0];
    const float* target = (const float*)d_in[1];
    float* out = (float*)d_out;
    const int planes = in_sizes[0] / PLANE;     // 48

    // 64 waves per plane (8 strips x 8 tiles of 64 rows), 4 waves/block.
    dim3 grid(planes * 16);                     // 768 blocks = 3 per CU
    CombinedLossSSIMCharbMSE_81372450390186_kernel<<<grid, dim3(256), 0, stream>>>(
        pred, target, out);
}